// Round 1
// baseline (651.974 us; speedup 1.0000x reference)
//
#include <hip/hip_runtime.h>

#define IN_DIM 40
#define HID 64
#define TSTEPS 500

typedef _Float16 half2v __attribute__((ext_vector_type(2)));
typedef float    float2v __attribute__((ext_vector_type(2)));

__device__ __forceinline__ float sigmoid_fast(float x) {
    return __builtin_amdgcn_rcpf(1.0f + __expf(-x));
}

__device__ __forceinline__ float tanh_fast(float x) {
    float ax = fabsf(x);
    float e = __expf(-2.0f * ax);
    float r = (1.0f - e) * __builtin_amdgcn_rcpf(1.0f + e);
    return copysignf(r, x);
}

__device__ __forceinline__ float dot2(uint w, uint hv, float acc) {
#if __has_builtin(__builtin_amdgcn_fdot2)
    return __builtin_amdgcn_fdot2(__builtin_bit_cast(half2v, w),
                                  __builtin_bit_cast(half2v, hv), acc, false);
#else
    half2v a = __builtin_bit_cast(half2v, w);
    half2v b = __builtin_bit_cast(half2v, hv);
    return acc + (float)a.x * (float)b.x + (float)a.y * (float)b.y;
#endif
}

__device__ __forceinline__ float2v pk_fma(float2v a, float2v b, float2v c) {
#if __has_builtin(__builtin_elementwise_fma)
    return __builtin_elementwise_fma(a, b, c);   // -> v_pk_fma_f32 on gfx950
#else
    return a * b + c;                            // -ffp-contract=fast fuses
#endif
}

// keep a 64-bit vector value pinned in VGPRs without relying on "+v"(v2f32) asm
__device__ __forceinline__ void keepalive64(float2v& v) {
    double d = __builtin_bit_cast(double, v);
    asm volatile("" : "+v"(d));
    v = __builtin_bit_cast(float2v, d);
}

__global__ __launch_bounds__(64, 1)
void lstm_fused(const float* __restrict__ x,
                const float* __restrict__ W_ih,
                const float* __restrict__ W_hh,
                const float* __restrict__ b_ih,
                const float* __restrict__ b_hh,
                const float* __restrict__ fc1_w,
                const float* __restrict__ fc1_b,
                const float* __restrict__ fc2_w,
                const float* __restrict__ fc2_b,
                float* __restrict__ out)
{
    const int b    = blockIdx.x;        // one batch element per 64-thread block (1 wave)
    const int lane = threadIdx.x & 63;  // hidden unit owned by this lane

    // ---- per-lane weights: all 4 gate rows for unit `lane` ----
    // W_ih rows: f32 pairs (4*20 = 80 pairs = 160 VGPRs) for v_pk_fma_f32
    float2v w_ih[4][IN_DIM / 2];
    // W_hh rows: packed f16 pairs (4*32 = 128 VGPRs) for v_dot2_f32_f16
    uint w_hh16[4][HID / 2];
    float bias[4];

    #pragma unroll
    for (int g = 0; g < 4; ++g) {
        const int j = g * HID + lane;
        const float4* p = reinterpret_cast<const float4*>(W_ih + (size_t)j * IN_DIM);
        #pragma unroll
        for (int i = 0; i < IN_DIM / 4; ++i) {
            float4 v = p[i];
            w_ih[g][2 * i + 0] = float2v{v.x, v.y};
            w_ih[g][2 * i + 1] = float2v{v.z, v.w};
        }
        const float4* q = reinterpret_cast<const float4*>(W_hh + (size_t)j * HID);
        #pragma unroll
        for (int i = 0; i < HID / 4; ++i) {
            float4 v = q[i];
            half2v lo = { (_Float16)v.x, (_Float16)v.y };
            half2v hi = { (_Float16)v.z, (_Float16)v.w };
            w_hh16[g][2 * i + 0] = __builtin_bit_cast(uint, lo);
            w_hh16[g][2 * i + 1] = __builtin_bit_cast(uint, hi);
        }
        bias[g] = b_ih[j] + b_hh[j];
    }
    #pragma unroll
    for (int g = 0; g < 4; ++g) {
        #pragma unroll
        for (int i = 0; i < IN_DIM / 2; ++i) keepalive64(w_ih[g][i]);
        #pragma unroll
        for (int i = 0; i < HID / 2; ++i)    asm volatile("" : "+v"(w_hh16[g][i]));
    }

    __shared__ __align__(16) uint  h16_lds[HID / 2];  // packed f16 h (128 B)
    __shared__ __align__(16) float h32_lds[HID];      // f32 h for epilogue

    if (lane < HID / 2) h16_lds[lane] = 0u;           // h0 = 0
    __syncthreads();                                  // one-time; block = 1 wave

    const float* xb = x + (size_t)b * TSTEPS * IN_DIM;

    float cst = 0.0f, hreg = 0.0f;

    // x_t is wave-uniform: load as float4, split into pk pairs
    auto ldx = [&](float2v (&xv)[IN_DIM / 2], int t) {
        const float4* xt = reinterpret_cast<const float4*>(xb + (size_t)t * IN_DIM);
        #pragma unroll
        for (int i = 0; i < IN_DIM / 4; ++i) {
            float4 q = xt[i];
            xv[2 * i + 0] = float2v{q.x, q.y};
            xv[2 * i + 1] = float2v{q.z, q.w};
        }
    };

    auto step = [&](const float2v (&xv)[IN_DIM / 2],
                    float2v (&xp)[IN_DIM / 2], int tpre) {
        // prefetch next timestep's x (hides global latency under this step's VALU)
        ldx(xp, tpre);

        // broadcast-read h_{t-1} (packed f16): 8x ds_read_b128, conflict-free
        uint hv[HID / 2];
        #pragma unroll
        for (int r = 0; r < HID / 8; ++r) {
            uint4 q = reinterpret_cast<const uint4*>(h16_lds)[r];
            hv[4 * r + 0] = q.x; hv[4 * r + 1] = q.y;
            hv[4 * r + 2] = q.z; hv[4 * r + 3] = q.w;
        }

        float z[4];
        #pragma unroll
        for (int g = 0; g < 4; ++g) {
            // z_g = bias + W_ih[g]·x_t   (f32 packed FMA, 20 instr)
            float2v a0 = {bias[g], 0.0f};
            float2v a1 = {0.0f, 0.0f};
            #pragma unroll
            for (int i = 0; i < IN_DIM / 2; i += 2) {
                a0 = pk_fma(xv[i + 0], w_ih[g][i + 0], a0);
                a1 = pk_fma(xv[i + 1], w_ih[g][i + 1], a1);
            }
            //       + W_hh[g]·h_{t-1}   (f16 dot2, 32 instr)
            float d0 = 0.f, d1 = 0.f, d2 = 0.f, d3 = 0.f;
            #pragma unroll
            for (int k = 0; k < HID / 2; k += 4) {
                d0 = dot2(w_hh16[g][k + 0], hv[k + 0], d0);
                d1 = dot2(w_hh16[g][k + 1], hv[k + 1], d1);
                d2 = dot2(w_hh16[g][k + 2], hv[k + 2], d2);
                d3 = dot2(w_hh16[g][k + 3], hv[k + 3], d3);
            }
            float2v a = a0 + a1;
            z[g] = (a.x + a.y) + ((d0 + d1) + (d2 + d3));
        }

        float iv = sigmoid_fast(z[0]);
        float fv = sigmoid_fast(z[1]);
        float gv = tanh_fast(z[2]);
        float ov = sigmoid_fast(z[3]);
        cst  = fmaf(fv, cst, iv * gv);
        hreg = ov * tanh_fast(cst);

        // publish h[lane] as f16: single ds_write_b16, no shuffle, no barrier
        _Float16 hf = (_Float16)hreg;
        reinterpret_cast<unsigned short*>(h16_lds)[lane] =
            __builtin_bit_cast(unsigned short, hf);
    };

    float2v xA[IN_DIM / 2], xB[IN_DIM / 2];
    ldx(xA, 0);

    #pragma unroll 1
    for (int t = 0; t < TSTEPS; t += 2) {
        step(xA, xB, t + 1);
        step(xB, xA, (t + 2 < TSTEPS) ? t + 2 : 0);   // clamped dummy prefetch at end
    }

    // ---- epilogue: fc1 + relu + fc2, full f32 h ----
    h32_lds[lane] = hreg;
    __syncthreads();

    float acc = fc1_b[lane];
    const float4* fw = reinterpret_cast<const float4*>(fc1_w + (size_t)lane * HID);
    #pragma unroll
    for (int kk = 0; kk < HID / 4; ++kk) {
        float4 w = fw[kk];
        float4 h = reinterpret_cast<const float4*>(h32_lds)[kk];
        acc = fmaf(w.x, h.x, acc);
        acc = fmaf(w.y, h.y, acc);
        acc = fmaf(w.z, h.z, acc);
        acc = fmaf(w.w, h.w, acc);
    }
    float r  = fmaxf(acc, 0.0f);
    float p0 = fc2_w[lane] * r;
    float p1 = fc2_w[HID + lane] * r;
    #pragma unroll
    for (int s = 32; s > 0; s >>= 1) {
        p0 += __shfl_xor(p0, s, 64);
        p1 += __shfl_xor(p1, s, 64);
    }
    if (lane == 0) {
        out[(size_t)b * 2 + 0] = p0 + fc2_b[0];
        out[(size_t)b * 2 + 1] = p1 + fc2_b[1];
    }
}

extern "C" void kernel_launch(void* const* d_in, const int* in_sizes, int n_in,
                              void* d_out, int out_size, void* d_ws, size_t ws_size,
                              hipStream_t stream) {
    const float* x     = (const float*)d_in[0];
    const float* W_ih  = (const float*)d_in[1];
    const float* W_hh  = (const float*)d_in[2];
    const float* b_ih  = (const float*)d_in[3];
    const float* b_hh  = (const float*)d_in[4];
    const float* fc1_w = (const float*)d_in[5];
    const float* fc1_b = (const float*)d_in[6];
    const float* fc2_w = (const float*)d_in[7];
    const float* fc2_b = (const float*)d_in[8];
    float* out = (float*)d_out;

    const int B = in_sizes[0] / (TSTEPS * IN_DIM);   // 1024
    lstm_fused<<<B, 64, 0, stream>>>(x, W_ih, W_hh, b_ih, b_hh,
                                     fc1_w, fc1_b, fc2_w, fc2_b, out);
}

// Round 2
// 626.769 us; speedup vs baseline: 1.0402x; 1.0402x over previous
//
#include <hip/hip_runtime.h>

#define IN_DIM 40
#define HID 64
#define TSTEPS 500
#define GATES 4

typedef _Float16 half2v __attribute__((ext_vector_type(2)));
typedef float    float2v __attribute__((ext_vector_type(2)));

__device__ __forceinline__ float sigmoid_fast(float x) {
    return __builtin_amdgcn_rcpf(1.0f + __expf(-x));
}

__device__ __forceinline__ float tanh_fast(float x) {
    float ax = fabsf(x);
    float e = __expf(-2.0f * ax);
    float r = (1.0f - e) * __builtin_amdgcn_rcpf(1.0f + e);
    return copysignf(r, x);
}

__device__ __forceinline__ float dot2(uint w, uint hv, float acc) {
#if __has_builtin(__builtin_amdgcn_fdot2)
    return __builtin_amdgcn_fdot2(__builtin_bit_cast(half2v, w),
                                  __builtin_bit_cast(half2v, hv), acc, false);
#else
    half2v a = __builtin_bit_cast(half2v, w);
    half2v b = __builtin_bit_cast(half2v, hv);
    return acc + (float)a.x * (float)b.x + (float)a.y * (float)b.y;
#endif
}

__device__ __forceinline__ float2v pk_fma(float2v a, float2v b, float2v c) {
#if __has_builtin(__builtin_elementwise_fma)
    return __builtin_elementwise_fma(a, b, c);   // v_pk_fma_f32
#else
    return a * b + c;
#endif
}

// ---------------- Kernel A: x_proj = W_ih . x_t + (b_ih + b_hh), f32 math, f16 store --------
// Layout: xp[b][tl][gate*64+u]  (f16), tl = t - t0, stride GATES*HID per timestep.
__global__ __launch_bounds__(256, 4)
void xproj_kernel(const float* __restrict__ x,
                  const float* __restrict__ W_ih,
                  const float* __restrict__ b_ih,
                  const float* __restrict__ b_hh,
                  unsigned short* __restrict__ xp,
                  int t0, int tc, int P, int rows_pb)
{
    const int g = threadIdx.x >> 6;
    const int u = threadIdx.x & 63;
    const int j = g * HID + u;
    const int b  = blockIdx.x / P;
    const int r0 = (blockIdx.x % P) * rows_pb;
    int rows = tc - r0;
    if (rows > rows_pb) rows = rows_pb;
    if (rows <= 0) return;

    float2v w[IN_DIM / 2];
    const float4* wp = reinterpret_cast<const float4*>(W_ih + (size_t)j * IN_DIM);
    #pragma unroll
    for (int i = 0; i < IN_DIM / 4; ++i) {
        float4 v = wp[i];
        w[2 * i + 0] = float2v{v.x, v.y};
        w[2 * i + 1] = float2v{v.z, v.w};
    }
    const float bias = b_ih[j] + b_hh[j];

    const float* xr = x + ((size_t)b * TSTEPS + (size_t)(t0 + r0)) * IN_DIM;
    unsigned short* op = xp + ((size_t)b * tc + r0) * (GATES * HID) + j;

    for (int r = 0; r < rows; ++r) {
        const float4* xt = reinterpret_cast<const float4*>(xr);
        float2v a0 = {bias, 0.0f};
        float2v a1 = {0.0f, 0.0f};
        #pragma unroll
        for (int i = 0; i < IN_DIM / 4; ++i) {
            float4 q = xt[i];
            a0 = pk_fma(float2v{q.x, q.y}, w[2 * i + 0], a0);
            a1 = pk_fma(float2v{q.z, q.w}, w[2 * i + 1], a1);
        }
        float2v s = a0 + a1;
        float z = s.x + s.y;
        op[0] = __builtin_bit_cast(unsigned short, (_Float16)z);
        xr += IN_DIM;
        op += GATES * HID;
    }
}

// ---------------- Kernel B: serial recurrence, 1 wave per batch element, no barriers --------
__global__ __launch_bounds__(64, 1)
void lstm_recur(const unsigned short* __restrict__ xp,
                const float* __restrict__ W_hh,
                const float* __restrict__ fc1_w,
                const float* __restrict__ fc1_b,
                const float* __restrict__ fc2_w,
                const float* __restrict__ fc2_b,
                float* __restrict__ c_state,
                float* __restrict__ h_state,
                float* __restrict__ out,
                int tc, int first, int last)
{
    const int b    = blockIdx.x;
    const int lane = threadIdx.x & 63;

    // W_hh rows for all 4 gates of unit `lane`: packed f16 pairs (128 VGPRs)
    uint w16[GATES][HID / 2];
    #pragma unroll
    for (int g = 0; g < GATES; ++g) {
        const float4* q = reinterpret_cast<const float4*>(W_hh + (size_t)(g * HID + lane) * HID);
        #pragma unroll
        for (int i = 0; i < HID / 4; ++i) {
            float4 v = q[i];
            half2v lo = { (_Float16)v.x, (_Float16)v.y };
            half2v hi = { (_Float16)v.z, (_Float16)v.w };
            w16[g][2 * i + 0] = __builtin_bit_cast(uint, lo);
            w16[g][2 * i + 1] = __builtin_bit_cast(uint, hi);
        }
    }
    #pragma unroll
    for (int g = 0; g < GATES; ++g)
        #pragma unroll
        for (int i = 0; i < HID / 2; ++i) asm volatile("" : "+v"(w16[g][i]));

    __shared__ __align__(16) unsigned short h16[HID];
    __shared__ __align__(16) float h32[HID];

    float c, h;
    if (first) { c = 0.0f; h = 0.0f; }
    else       { c = c_state[b * HID + lane]; h = h_state[b * HID + lane]; }
    h16[lane] = __builtin_bit_cast(unsigned short, (_Float16)h);
    __syncthreads();   // one-time (block = 1 wave)

    const unsigned short* xb = xp + (size_t)b * tc * (GATES * HID) + lane;

    float zx[GATES], zxn[GATES];
    #pragma unroll
    for (int g = 0; g < GATES; ++g)
        zx[g] = (float)__builtin_bit_cast(_Float16, xb[g * HID]);

    #pragma unroll 1
    for (int t = 0; t < tc; ++t) {
        // prefetch next step's x_proj (4 coalesced ushort loads, clamped at the tail)
        const unsigned short* xn = xb + (size_t)((t + 1 < tc) ? t + 1 : t) * (GATES * HID);
        #pragma unroll
        for (int g = 0; g < GATES; ++g)
            zxn[g] = (float)__builtin_bit_cast(_Float16, xn[g * HID]);

        // broadcast-read h_{t-1} as packed f16: 8x ds_read_b128, conflict-free
        uint hv[HID / 2];
        #pragma unroll
        for (int r = 0; r < HID / 8; ++r) {
            uint4 q = reinterpret_cast<const uint4*>(h16)[r];
            hv[4 * r + 0] = q.x; hv[4 * r + 1] = q.y;
            hv[4 * r + 2] = q.z; hv[4 * r + 3] = q.w;
        }

        float z[GATES];
        #pragma unroll
        for (int g = 0; g < GATES; ++g) {
            float d0 = zx[g], d1 = 0.f, d2 = 0.f, d3 = 0.f;
            #pragma unroll
            for (int k = 0; k < HID / 2; k += 4) {
                d0 = dot2(w16[g][k + 0], hv[k + 0], d0);
                d1 = dot2(w16[g][k + 1], hv[k + 1], d1);
                d2 = dot2(w16[g][k + 2], hv[k + 2], d2);
                d3 = dot2(w16[g][k + 3], hv[k + 3], d3);
            }
            z[g] = (d0 + d1) + (d2 + d3);
        }

        float iv = sigmoid_fast(z[0]);
        float fv = sigmoid_fast(z[1]);
        float gv = tanh_fast(z[2]);
        float ov = sigmoid_fast(z[3]);
        c = fmaf(fv, c, iv * gv);
        h = ov * tanh_fast(c);

        // publish h[lane] as f16; same-wave DS ops are ordered -> no barrier
        h16[lane] = __builtin_bit_cast(unsigned short, (_Float16)h);

        #pragma unroll
        for (int g = 0; g < GATES; ++g) zx[g] = zxn[g];
    }

    if (!last) {
        c_state[b * HID + lane] = c;
        h_state[b * HID + lane] = h;
        return;
    }

    // ---- epilogue: fc1 + relu + fc2 (f32 h) ----
    h32[lane] = h;
    __syncthreads();

    float acc = fc1_b[lane];
    const float4* fw = reinterpret_cast<const float4*>(fc1_w + (size_t)lane * HID);
    #pragma unroll
    for (int kk = 0; kk < HID / 4; ++kk) {
        float4 wv = fw[kk];
        float4 hh = reinterpret_cast<const float4*>(h32)[kk];
        acc = fmaf(wv.x, hh.x, acc);
        acc = fmaf(wv.y, hh.y, acc);
        acc = fmaf(wv.z, hh.z, acc);
        acc = fmaf(wv.w, hh.w, acc);
    }
    float r  = fmaxf(acc, 0.0f);
    float p0 = fc2_w[lane] * r;
    float p1 = fc2_w[HID + lane] * r;
    #pragma unroll
    for (int s = 32; s > 0; s >>= 1) {
        p0 += __shfl_xor(p0, s, 64);
        p1 += __shfl_xor(p1, s, 64);
    }
    if (lane == 0) {
        out[(size_t)b * 2 + 0] = p0 + fc2_b[0];
        out[(size_t)b * 2 + 1] = p1 + fc2_b[1];
    }
}

extern "C" void kernel_launch(void* const* d_in, const int* in_sizes, int n_in,
                              void* d_out, int out_size, void* d_ws, size_t ws_size,
                              hipStream_t stream) {
    const float* x     = (const float*)d_in[0];
    const float* W_ih  = (const float*)d_in[1];
    const float* W_hh  = (const float*)d_in[2];
    const float* b_ih  = (const float*)d_in[3];
    const float* b_hh  = (const float*)d_in[4];
    const float* fc1_w = (const float*)d_in[5];
    const float* fc1_b = (const float*)d_in[6];
    const float* fc2_w = (const float*)d_in[7];
    const float* fc2_b = (const float*)d_in[8];
    float* out = (float*)d_out;

    const int B = in_sizes[0] / (TSTEPS * IN_DIM);   // 1024

    // workspace: [c_state | h_state | x_proj chunk (f16)]
    float* c_state = (float*)d_ws;
    float* h_state = c_state + (size_t)B * HID;
    unsigned short* xproj = (unsigned short*)(h_state + (size_t)B * HID);

    const size_t state_bytes = (size_t)B * HID * 4 * 2;
    const size_t per_t_bytes = (size_t)B * GATES * HID * 2;

    int TC = TSTEPS;
    if (ws_size > state_bytes) {
        size_t fit = (ws_size - state_bytes) / per_t_bytes;
        if (fit < (size_t)TC) TC = (int)fit;
    } else {
        TC = 1;
    }
    if (TC < 1) TC = 1;

    int t0 = 0;
    while (t0 < TSTEPS) {
        int tc = TSTEPS - t0;
        if (tc > TC) tc = TC;
        int P = (tc + 124) / 125;            // ~125 rows per block
        int rows_pb = (tc + P - 1) / P;
        xproj_kernel<<<B * P, 256, 0, stream>>>(x, W_ih, b_ih, b_hh, xproj,
                                                t0, tc, P, rows_pb);
        lstm_recur<<<B, 64, 0, stream>>>(xproj, W_hh, fc1_w, fc1_b, fc2_w, fc2_b,
                                         c_state, h_state, out,
                                         tc, t0 == 0 ? 1 : 0,
                                         (t0 + tc == TSTEPS) ? 1 : 0);
        t0 += tc;
    }
}

// Round 3
// 402.431 us; speedup vs baseline: 1.6201x; 1.5575x over previous
//
#include <hip/hip_runtime.h>

#define IN_DIM 40
#define HID 64
#define TSTEPS 500

typedef _Float16 half2v __attribute__((ext_vector_type(2)));

__device__ __forceinline__ float sigmoid_fast(float x) {
    return __builtin_amdgcn_rcpf(1.0f + __expf(-x));
}

__device__ __forceinline__ float tanh_fast(float x) {
    float ax = fabsf(x);
    float e = __expf(-2.0f * ax);
    float r = (1.0f - e) * __builtin_amdgcn_rcpf(1.0f + e);
    return copysignf(r, x);
}

__device__ __forceinline__ float dot2(uint w, uint hv, float acc) {
#if __has_builtin(__builtin_amdgcn_fdot2)
    return __builtin_amdgcn_fdot2(__builtin_bit_cast(half2v, w),
                                  __builtin_bit_cast(half2v, hv), acc, false);
#else
    half2v a = __builtin_bit_cast(half2v, w);
    half2v b = __builtin_bit_cast(half2v, hv);
    return acc + (float)a.x * (float)b.x + (float)a.y * (float)b.y;
#endif
}

// ---------------- Kernel A: cast x to f16 (contiguous layout preserved) ----------------
__global__ __launch_bounds__(256)
void xcast_kernel(const float* __restrict__ x, unsigned short* __restrict__ xf, int n4)
{
    int idx    = blockIdx.x * 256 + threadIdx.x;
    int stride = gridDim.x * 256;
    for (int i = idx; i < n4; i += stride) {
        float4 v = reinterpret_cast<const float4*>(x)[i];
        half2v a = { (_Float16)v.x, (_Float16)v.y };
        half2v bb = { (_Float16)v.z, (_Float16)v.w };
        uint2 o = { __builtin_bit_cast(uint, a), __builtin_bit_cast(uint, bb) };
        reinterpret_cast<uint2*>(xf)[i] = o;
    }
}

// ---------------- Kernel B: fused recurrence, 2 waves per chain (gate-split) ----------
// wave 0: gates i(0), f(1).  wave 1: gates g(2), o(3).
__global__ __launch_bounds__(128, 2)
void lstm_recur(const unsigned short* __restrict__ xf,
                const float* __restrict__ W_ih,
                const float* __restrict__ W_hh,
                const float* __restrict__ b_ih,
                const float* __restrict__ b_hh,
                const float* __restrict__ fc1_w,
                const float* __restrict__ fc1_b,
                const float* __restrict__ fc2_w,
                const float* __restrict__ fc2_b,
                float* __restrict__ out)
{
    const int b    = blockIdx.x;
    const int w    = threadIdx.x >> 6;      // wave id 0/1
    const int lane = threadIdx.x & 63;

    // ---- per-lane weights for this wave's two gates (g = 2w, 2w+1), packed f16 ----
    uint wih[2][IN_DIM / 2];   // 40 VGPRs
    uint whh[2][HID / 2];      // 64 VGPRs
    float bias[2];
    #pragma unroll
    for (int gg = 0; gg < 2; ++gg) {
        const int j = (2 * w + gg) * HID + lane;
        const float4* p = reinterpret_cast<const float4*>(W_ih + (size_t)j * IN_DIM);
        #pragma unroll
        for (int i = 0; i < IN_DIM / 4; ++i) {
            float4 v = p[i];
            half2v lo = { (_Float16)v.x, (_Float16)v.y };
            half2v hi = { (_Float16)v.z, (_Float16)v.w };
            wih[gg][2 * i + 0] = __builtin_bit_cast(uint, lo);
            wih[gg][2 * i + 1] = __builtin_bit_cast(uint, hi);
        }
        const float4* q = reinterpret_cast<const float4*>(W_hh + (size_t)j * HID);
        #pragma unroll
        for (int i = 0; i < HID / 4; ++i) {
            float4 v = q[i];
            half2v lo = { (_Float16)v.x, (_Float16)v.y };
            half2v hi = { (_Float16)v.z, (_Float16)v.w };
            whh[gg][2 * i + 0] = __builtin_bit_cast(uint, lo);
            whh[gg][2 * i + 1] = __builtin_bit_cast(uint, hi);
        }
        bias[gg] = b_ih[j] + b_hh[j];
    }

    __shared__ __align__(16) unsigned short h16[2][HID];  // per-wave private h copy
    __shared__ float a_x[2][4][HID];                      // [parity][gate][unit]
    __shared__ __align__(16) float h32[HID];

    h16[w][lane] = 0u;     // own copy; same-wave ordering suffices
    float c = 0.0f, h = 0.0f;

    const unsigned short* xrow = xf + (size_t)b * TSTEPS * IN_DIM;

    auto ldx = [&](uint (&xv)[IN_DIM / 2], int t) {
        const uint4* p = reinterpret_cast<const uint4*>(xrow + (size_t)t * IN_DIM);
        #pragma unroll
        for (int i = 0; i < IN_DIM / 8; ++i) {   // 5 x 16B
            uint4 q = p[i];
            xv[4 * i + 0] = q.x; xv[4 * i + 1] = q.y;
            xv[4 * i + 2] = q.z; xv[4 * i + 3] = q.w;
        }
    };

    auto step = [&](const uint (&xv)[IN_DIM / 2], uint (&xn)[IN_DIM / 2],
                    int tn, int par) {
        // prefetch next x_t (wave-uniform 80B)
        ldx(xn, tn);

        // own h copy: 8x ds_read_b128 broadcast
        uint hv[HID / 2];
        #pragma unroll
        for (int r = 0; r < HID / 8; ++r) {
            uint4 q = reinterpret_cast<const uint4*>(h16[w])[r];
            hv[4 * r + 0] = q.x; hv[4 * r + 1] = q.y;
            hv[4 * r + 2] = q.z; hv[4 * r + 3] = q.w;
        }

        float z[2];
        #pragma unroll
        for (int gg = 0; gg < 2; ++gg) {
            float d0 = bias[gg], d1 = 0.f, d2 = 0.f, d3 = 0.f;
            #pragma unroll
            for (int i = 0; i < IN_DIM / 2; i += 4) {       // 20 dot2 (x part)
                d0 = dot2(wih[gg][i + 0], xv[i + 0], d0);
                d1 = dot2(wih[gg][i + 1], xv[i + 1], d1);
                d2 = dot2(wih[gg][i + 2], xv[i + 2], d2);
                d3 = dot2(wih[gg][i + 3], xv[i + 3], d3);
            }
            #pragma unroll
            for (int k = 0; k < HID / 2; k += 4) {          // 32 dot2 (h part)
                d0 = dot2(whh[gg][k + 0], hv[k + 0], d0);
                d1 = dot2(whh[gg][k + 1], hv[k + 1], d1);
                d2 = dot2(whh[gg][k + 2], hv[k + 2], d2);
                d3 = dot2(whh[gg][k + 3], hv[k + 3], d3);
            }
            z[gg] = (d0 + d1) + (d2 + d3);
        }

        // own activations (wave-uniform branch)
        float a0, a1;
        if (w == 0) { a0 = sigmoid_fast(z[0]); a1 = sigmoid_fast(z[1]); } // i, f
        else        { a0 = tanh_fast(z[0]);    a1 = sigmoid_fast(z[1]); } // g, o

        a_x[par][2 * w + 0][lane] = a0;
        a_x[par][2 * w + 1][lane] = a1;
        __syncthreads();                       // the ONLY barrier per step

        float iv, fv, gv, ov;
        if (w == 0) {
            iv = a0; fv = a1;
            gv = a_x[par][2][lane]; ov = a_x[par][3][lane];
        } else {
            gv = a0; ov = a1;
            iv = a_x[par][0][lane]; fv = a_x[par][1][lane];
        }
        c = fmaf(fv, c, iv * gv);
        h = ov * tanh_fast(c);

        // publish h to OWN copy only (read next step by same wave -> no barrier)
        h16[w][lane] = __builtin_bit_cast(unsigned short, (_Float16)h);
    };

    uint xA[IN_DIM / 2], xB[IN_DIM / 2];
    ldx(xA, 0);

    #pragma unroll 1
    for (int t = 0; t < TSTEPS; t += 2) {
        step(xA, xB, t + 1, 0);
        step(xB, xA, (t + 2 < TSTEPS) ? t + 2 : TSTEPS - 1, 1);
    }

    // ---- epilogue: wave 0 only (it has h[lane]); same-wave LDS, no barrier ----
    if (w == 0) {
        h32[lane] = h;
        float acc = fc1_b[lane];
        const float4* fw = reinterpret_cast<const float4*>(fc1_w + (size_t)lane * HID);
        #pragma unroll
        for (int kk = 0; kk < HID / 4; ++kk) {
            float4 wv = fw[kk];
            float4 hh = reinterpret_cast<const float4*>(h32)[kk];
            acc = fmaf(wv.x, hh.x, acc);
            acc = fmaf(wv.y, hh.y, acc);
            acc = fmaf(wv.z, hh.z, acc);
            acc = fmaf(wv.w, hh.w, acc);
        }
        float r  = fmaxf(acc, 0.0f);
        float p0 = fc2_w[lane] * r;
        float p1 = fc2_w[HID + lane] * r;
        #pragma unroll
        for (int s = 32; s > 0; s >>= 1) {
            p0 += __shfl_xor(p0, s, 64);
            p1 += __shfl_xor(p1, s, 64);
        }
        if (lane == 0) {
            out[(size_t)b * 2 + 0] = p0 + fc2_b[0];
            out[(size_t)b * 2 + 1] = p1 + fc2_b[1];
        }
    }
}

extern "C" void kernel_launch(void* const* d_in, const int* in_sizes, int n_in,
                              void* d_out, int out_size, void* d_ws, size_t ws_size,
                              hipStream_t stream) {
    const float* x     = (const float*)d_in[0];
    const float* W_ih  = (const float*)d_in[1];
    const float* W_hh  = (const float*)d_in[2];
    const float* b_ih  = (const float*)d_in[3];
    const float* b_hh  = (const float*)d_in[4];
    const float* fc1_w = (const float*)d_in[5];
    const float* fc1_b = (const float*)d_in[6];
    const float* fc2_w = (const float*)d_in[7];
    const float* fc2_b = (const float*)d_in[8];
    float* out = (float*)d_out;

    const int B = in_sizes[0] / (TSTEPS * IN_DIM);   // 1024

    unsigned short* xf16 = (unsigned short*)d_ws;    // 40 MB f16 copy of x

    const int n4 = B * TSTEPS * IN_DIM / 4;
    xcast_kernel<<<2048, 256, 0, stream>>>(x, xf16, n4);
    lstm_recur<<<B, 128, 0, stream>>>(xf16, W_ih, W_hh, b_ih, b_hh,
                                      fc1_w, fc1_b, fc2_w, fc2_b, out);
}

// Round 4
// 379.585 us; speedup vs baseline: 1.7176x; 1.0602x over previous
//
#include <hip/hip_runtime.h>

#define IN_DIM 40
#define HID 64
#define TSTEPS 500

typedef _Float16 half2v __attribute__((ext_vector_type(2)));

__device__ __forceinline__ float sigmoid_fast(float x) {
    return __builtin_amdgcn_rcpf(1.0f + __expf(-x));
}

__device__ __forceinline__ float tanh_fast(float x) {
    float ax = fabsf(x);
    float e = __expf(-2.0f * ax);
    float r = (1.0f - e) * __builtin_amdgcn_rcpf(1.0f + e);
    return copysignf(r, x);
}

__device__ __forceinline__ float dot2(uint w, uint hv, float acc) {
#if __has_builtin(__builtin_amdgcn_fdot2)
    return __builtin_amdgcn_fdot2(__builtin_bit_cast(half2v, w),
                                  __builtin_bit_cast(half2v, hv), acc, false);
#else
    half2v a = __builtin_bit_cast(half2v, w);
    half2v b = __builtin_bit_cast(half2v, hv);
    return acc + (float)a.x * (float)b.x + (float)a.y * (float)b.y;
#endif
}

// ---------------- Kernel A: cast x to f16 (contiguous layout preserved) ----------------
__global__ __launch_bounds__(256)
void xcast_kernel(const float* __restrict__ x, unsigned short* __restrict__ xf, int n4)
{
    int idx    = blockIdx.x * 256 + threadIdx.x;
    int stride = gridDim.x * 256;
    for (int i = idx; i < n4; i += stride) {
        float4 v = reinterpret_cast<const float4*>(x)[i];
        half2v a = { (_Float16)v.x, (_Float16)v.y };
        half2v bb = { (_Float16)v.z, (_Float16)v.w };
        uint2 o = { __builtin_bit_cast(uint, a), __builtin_bit_cast(uint, bb) };
        reinterpret_cast<uint2*>(xf)[i] = o;
    }
}

// ---------------- Kernel B: recurrence; x fully LDS-resident; unit-split 2 waves ------
// wave w owns units [32w, 32w+32). lane<32: gates i,f ; lane>=32: gates g,o.
// Steady-state loop has ZERO global memory ops -> per-step __syncthreads drain is free.
__global__ __launch_bounds__(128, 2)
void lstm_recur(const unsigned short* __restrict__ xf,
                const float* __restrict__ W_ih,
                const float* __restrict__ W_hh,
                const float* __restrict__ b_ih,
                const float* __restrict__ b_hh,
                const float* __restrict__ fc1_w,
                const float* __restrict__ fc1_b,
                const float* __restrict__ fc2_w,
                const float* __restrict__ fc2_b,
                float* __restrict__ out)
{
    const int b    = blockIdx.x;
    const int tid  = threadIdx.x;
    const int w    = tid >> 6;
    const int lane = tid & 63;
    const int ul   = lane & 31;
    const int unit = w * 32 + ul;       // hidden unit owned by this lane
    const bool hi  = (lane >= 32);      // gate pair: lo=(i,f), hi=(g,o)

    __shared__ __align__(16) unsigned short xlds[TSTEPS * IN_DIM];  // 40000 B
    __shared__ __align__(16) unsigned short h16[2][HID];            // 256 B, parity dbuf
    __shared__ __align__(16) float h32[HID];                        // 256 B (epilogue)

    // ---- stage whole x chain (f16) into LDS: 2500 uint4, 128 threads, 20 passes ----
    {
        const uint4* src = reinterpret_cast<const uint4*>(xf + (size_t)b * TSTEPS * IN_DIM);
        uint4* dst = reinterpret_cast<uint4*>(xlds);
        #pragma unroll
        for (int p = 0; p < 20; ++p) {
            int idx = p * 128 + tid;
            if (idx < (TSTEPS * IN_DIM * 2) / 16)   // 2500
                dst[idx] = src[idx];
        }
    }

    // ---- per-lane weights for this lane's two gates, packed f16 pairs ----
    uint wih[2][IN_DIM / 2];   // 40 VGPRs
    uint whh[2][HID / 2];      // 64 VGPRs
    float bias[2];
    const int gbase = hi ? 2 : 0;
    #pragma unroll
    for (int gg = 0; gg < 2; ++gg) {
        const int j = (gbase + gg) * HID + unit;
        const float4* p = reinterpret_cast<const float4*>(W_ih + (size_t)j * IN_DIM);
        #pragma unroll
        for (int i = 0; i < IN_DIM / 4; ++i) {
            float4 v = p[i];
            half2v lo = { (_Float16)v.x, (_Float16)v.y };
            half2v hh = { (_Float16)v.z, (_Float16)v.w };
            wih[gg][2 * i + 0] = __builtin_bit_cast(uint, lo);
            wih[gg][2 * i + 1] = __builtin_bit_cast(uint, hh);
        }
        const float4* q = reinterpret_cast<const float4*>(W_hh + (size_t)j * HID);
        #pragma unroll
        for (int i = 0; i < HID / 4; ++i) {
            float4 v = q[i];
            half2v lo = { (_Float16)v.x, (_Float16)v.y };
            half2v hh = { (_Float16)v.z, (_Float16)v.w };
            whh[gg][2 * i + 0] = __builtin_bit_cast(uint, lo);
            whh[gg][2 * i + 1] = __builtin_bit_cast(uint, hh);
        }
        bias[gg] = b_ih[j] + b_hh[j];
    }
    #pragma unroll
    for (int gg = 0; gg < 2; ++gg) {
        #pragma unroll
        for (int i = 0; i < IN_DIM / 2; ++i) asm volatile("" : "+v"(wih[gg][i]));
        #pragma unroll
        for (int i = 0; i < HID / 2; ++i)    asm volatile("" : "+v"(whh[gg][i]));
    }

    if (tid < HID) h16[0][tid] = 0u;       // h0 = 0
    __syncthreads();                       // staging + init complete (drains prologue)

    float c = 0.0f, h = 0.0f;

    // broadcast read of x_t from LDS: 5x ds_read_b128 (80 B, 16B-aligned since 80%16==0)
    auto ldx = [&](uint (&xv)[IN_DIM / 2], int t) {
        const uint4* p = reinterpret_cast<const uint4*>(xlds + (size_t)t * IN_DIM);
        #pragma unroll
        for (int i = 0; i < IN_DIM / 8; ++i) {
            uint4 q = p[i];
            xv[4 * i + 0] = q.x; xv[4 * i + 1] = q.y;
            xv[4 * i + 2] = q.z; xv[4 * i + 3] = q.w;
        }
    };

    auto step = [&](const uint (&xv)[IN_DIM / 2], uint (&xn)[IN_DIM / 2],
                    int tn, int par) {
        // h_{t-1}: 8x ds_read_b128 broadcast (issued first; latency hidden by x-dot2s)
        uint hv[HID / 2];
        #pragma unroll
        for (int r = 0; r < HID / 8; ++r) {
            uint4 q = reinterpret_cast<const uint4*>(&h16[par][0])[r];
            hv[4 * r + 0] = q.x; hv[4 * r + 1] = q.y;
            hv[4 * r + 2] = q.z; hv[4 * r + 3] = q.w;
        }
        // prefetch next step's x from LDS (consumed next step)
        ldx(xn, tn);

        float z[2];
        #pragma unroll
        for (int gg = 0; gg < 2; ++gg) {
            // x part first: operands are register-resident -> runs under hv latency
            float d0 = bias[gg], d1 = 0.f, d2 = 0.f, d3 = 0.f;
            #pragma unroll
            for (int i = 0; i < IN_DIM / 2; i += 4) {
                d0 = dot2(wih[gg][i + 0], xv[i + 0], d0);
                d1 = dot2(wih[gg][i + 1], xv[i + 1], d1);
                d2 = dot2(wih[gg][i + 2], xv[i + 2], d2);
                d3 = dot2(wih[gg][i + 3], xv[i + 3], d3);
            }
            #pragma unroll
            for (int k = 0; k < HID / 2; k += 4) {
                d0 = dot2(whh[gg][k + 0], hv[k + 0], d0);
                d1 = dot2(whh[gg][k + 1], hv[k + 1], d1);
                d2 = dot2(whh[gg][k + 2], hv[k + 2], d2);
                d3 = dot2(whh[gg][k + 3], hv[k + 3], d3);
            }
            z[gg] = (d0 + d1) + (d2 + d3);
        }

        // activations, branchless half-split:
        // a0 = hi ? tanh(z0) : sigmoid(z0)   (one exp);  a1 = sigmoid(z1) always
        float zz  = hi ? (-2.0f * fabsf(z[0])) : (-z[0]);
        float e0  = __expf(zz);
        float num = hi ? (1.0f - e0) : 1.0f;
        float r0  = num * __builtin_amdgcn_rcpf(1.0f + e0);
        float a0  = hi ? copysignf(r0, z[0]) : r0;
        float a1  = sigmoid_fast(z[1]);

        // exchange with partner half (same unit): pure in-wave shuffles
        float pa0 = __shfl_xor(a0, 32, 64);
        float pa1 = __shfl_xor(a1, 32, 64);
        float iv = hi ? pa0 : a0;
        float fv = hi ? pa1 : a1;
        float gv = hi ? a0 : pa0;
        float ov = hi ? a1 : pa1;

        c = fmaf(fv, c, iv * gv);        // both halves compute redundantly (consistent)
        h = ov * tanh_fast(c);

        // publish h for own unit into the other parity buffer
        if (!hi) {
            _Float16 hf = (_Float16)h;
            h16[par ^ 1][unit] = __builtin_bit_cast(unsigned short, hf);
        }
        __syncthreads();   // drain-free: no outstanding vmem in steady state
    };

    uint xA[IN_DIM / 2], xB[IN_DIM / 2];
    ldx(xA, 0);

    #pragma unroll 1
    for (int t = 0; t < TSTEPS; t += 2) {
        step(xA, xB, t + 1, 0);
        step(xB, xA, (t + 2 < TSTEPS) ? t + 2 : 0, 1);   // dummy in-bounds prefetch at tail
    }

    // ---- epilogue: gather h (f32), fc1 + relu + fc2 on wave 0 ----
    if (!hi) h32[unit] = h;
    __syncthreads();

    if (w == 0) {
        float acc = fc1_b[lane];
        const float4* fw = reinterpret_cast<const float4*>(fc1_w + (size_t)lane * HID);
        #pragma unroll
        for (int kk = 0; kk < HID / 4; ++kk) {
            float4 wv = fw[kk];
            float4 hh = reinterpret_cast<const float4*>(h32)[kk];
            acc = fmaf(wv.x, hh.x, acc);
            acc = fmaf(wv.y, hh.y, acc);
            acc = fmaf(wv.z, hh.z, acc);
            acc = fmaf(wv.w, hh.w, acc);
        }
        float r  = fmaxf(acc, 0.0f);
        float p0 = fc2_w[lane] * r;
        float p1 = fc2_w[HID + lane] * r;
        #pragma unroll
        for (int s = 32; s > 0; s >>= 1) {
            p0 += __shfl_xor(p0, s, 64);
            p1 += __shfl_xor(p1, s, 64);
        }
        if (lane == 0) {
            out[(size_t)b * 2 + 0] = p0 + fc2_b[0];
            out[(size_t)b * 2 + 1] = p1 + fc2_b[1];
        }
    }
}

extern "C" void kernel_launch(void* const* d_in, const int* in_sizes, int n_in,
                              void* d_out, int out_size, void* d_ws, size_t ws_size,
                              hipStream_t stream) {
    const float* x     = (const float*)d_in[0];
    const float* W_ih  = (const float*)d_in[1];
    const float* W_hh  = (const float*)d_in[2];
    const float* b_ih  = (const float*)d_in[3];
    const float* b_hh  = (const float*)d_in[4];
    const float* fc1_w = (const float*)d_in[5];
    const float* fc1_b = (const float*)d_in[6];
    const float* fc2_w = (const float*)d_in[7];
    const float* fc2_b = (const float*)d_in[8];
    float* out = (float*)d_out;

    const int B = in_sizes[0] / (TSTEPS * IN_DIM);   // 1024

    unsigned short* xf16 = (unsigned short*)d_ws;    // 40 MB f16 copy of x

    const int n4 = B * TSTEPS * IN_DIM / 4;
    xcast_kernel<<<2048, 256, 0, stream>>>(x, xf16, n4);
    lstm_recur<<<B, 128, 0, stream>>>(xf16, W_ih, W_hh, b_ih, b_hh,
                                      fc1_w, fc1_b, fc2_w, fc2_b, out);
}